// Round 1
// baseline (397.664 us; speedup 1.0000x reference)
//
#include <hip/hip_runtime.h>

// out[b,i,h,w] = w1 * (w >= s1      ? x[b,h,w-s1] : 0)
//              + w2 * (w + s2 < 512 ? x[b,h,w+s2] : 0)
// with s1 = (i+1)>>1, s2 = (i>>1)+1.   B=2, I=H=W=512.
// Write-BW bound: 1.07 GB store, ~2 MiB input (L2-resident).

__global__ __launch_bounds__(256) void StereoConv_kernel(
    const float* __restrict__ x,     // (2, 512, 512) == x[:,0]
    const float* __restrict__ w1p,   // scalar
    const float* __restrict__ w2p,   // scalar
    float4* __restrict__ out4)       // (2, 512, 512, 512) as float4[.., 128]
{
    const int tid = blockIdx.x * 256 + threadIdx.x;
    // layout: tid = (((b*512 + i)*512 + h)*128 + w4)
    const int w4 = tid & 127;          // float4 index along w
    const int h  = (tid >> 7) & 511;
    const int i  = (tid >> 16) & 511;
    const int b  = tid >> 25;

    const float w1 = w1p[0];
    const float w2 = w2p[0];
    const int s1 = (i + 1) >> 1;       // left shift amount
    const int s2 = (i >> 1) + 1;       // right shift amount

    const float* __restrict__ row = x + (((b << 9) + h) << 9);  // x[b,h,:]

    const int w0 = w4 << 2;
    float v[4];
#pragma unroll
    for (int k = 0; k < 4; ++k) {
        const int w = w0 + k;
        float acc = 0.0f;
        if (w >= s1)        acc += w1 * row[w - s1];
        if (w + s2 < 512)   acc += w2 * row[w + s2];
        v[k] = acc;
    }
    out4[tid] = make_float4(v[0], v[1], v[2], v[3]);
}

extern "C" void kernel_launch(void* const* d_in, const int* in_sizes, int n_in,
                              void* d_out, int out_size, void* d_ws, size_t ws_size,
                              hipStream_t stream) {
    const float* x  = (const float*)d_in[0];
    const float* w1 = (const float*)d_in[1];
    const float* w2 = (const float*)d_in[2];
    float4* out4 = (float4*)d_out;

    // total float4 elements: 2 * 512 * 512 * 128 = 33,554,432
    const int total4 = 2 * 512 * 512 * 128;
    const int threads = 256;
    const int blocks = total4 / threads;   // 131072
    StereoConv_kernel<<<blocks, threads, 0, stream>>>(x, w1, w2, out4);
}

// Round 2
// 396.719 us; speedup vs baseline: 1.0024x; 1.0024x over previous
//
#include <hip/hip_runtime.h>

// out[b,i,h,w] = w1 * (w >= s1      ? x[b,h,w-s1] : 0)
//              + w2 * (w + s2 < 512 ? x[b,h,w+s2] : 0)
// with s1 = (i+1)>>1, s2 = (i>>1)+1.   B=2, I=H=W=512.
//
// Write-BW bound: 1.074 GB store, ~2 MiB input (L2-resident).
// Round 2: grid-stride (2048 blocks), 128 float4 stores per thread to
// amortize wave launch/setup — round 1's 1-store-per-wave churned 262k
// workgroups at 2.7 TB/s vs fill's 6.4 TB/s on the same buffer.

__global__ __launch_bounds__(256) void StereoConv_kernel(
    const float* __restrict__ x,     // (2, 512, 512) == x[:,0]
    const float* __restrict__ w1p,   // scalar
    const float* __restrict__ w2p,   // scalar
    float4* __restrict__ out4)       // (2, 512, 512, 512) as float4[.., 128]
{
    const int tid = blockIdx.x * 256 + threadIdx.x;   // 0 .. 2^19-1
    // flat float4 index = (it << 19) | tid, it = 0..127
    // bits: w4 = [0:6], h = [7:15], i = [16:24], b = [25]
    const int w4  = tid & 127;         // loop-invariant
    const int h   = (tid >> 7) & 511;  // loop-invariant
    const int ilo = tid >> 16;         // low 3 bits of i, loop-invariant

    const float w1 = w1p[0];
    const float w2 = w2p[0];
    const int w0 = w4 << 2;

    for (int it = 0; it < 128; ++it) {
        const int i = ((it & 63) << 3) | ilo;
        const int b = it >> 6;
        const int s1 = (i + 1) >> 1;       // left shift amount
        const int s2 = (i >> 1) + 1;       // right shift amount
        const float* __restrict__ row = x + (((b << 9) + h) << 9);  // x[b,h,:]

        float v[4];
#pragma unroll
        for (int k = 0; k < 4; ++k) {
            const int w = w0 + k;
            const int i1 = w - s1;
            const int i2 = w + s2;
            // branchless: clamped load + value select (cndmask, no exec churn)
            const float a = row[i1 < 0 ? 0 : i1];
            const float c = row[i2 > 511 ? 511 : i2];
            const float av = (i1 >= 0)  ? a : 0.0f;
            const float cv = (i2 < 512) ? c : 0.0f;
            v[k] = w1 * av + w2 * cv;
        }
        out4[((size_t)it << 19) | (size_t)tid] = make_float4(v[0], v[1], v[2], v[3]);
    }
}

extern "C" void kernel_launch(void* const* d_in, const int* in_sizes, int n_in,
                              void* d_out, int out_size, void* d_ws, size_t ws_size,
                              hipStream_t stream) {
    const float* x  = (const float*)d_in[0];
    const float* w1 = (const float*)d_in[1];
    const float* w2 = (const float*)d_in[2];
    float4* out4 = (float4*)d_out;

    // total float4 elements: 2*512*512*128 = 2^26; 2048 blocks * 256 thr * 128 iters
    StereoConv_kernel<<<2048, 256, 0, stream>>>(x, w1, w2, out4);
}

// Round 4
// 199.993 us; speedup vs baseline: 1.9884x; 1.9837x over previous
//
#include <hip/hip_runtime.h>

// out[b,i,h,w] = w1 * (w-s1 >= 0 ? x[b,h,w-s1] : 0) + w2 * (w+s2 < 512 ? x[b,h,w+s2] : 0)
// s1 = (i+1)>>1, s2 = (i>>1)+1.  B=2, I=H=W=512.
//
// Round 3 (fixed): i-blocked by 8 (i0 = 8*it). Then
//   idx1 = W + k - ((d+1)>>1),  W = w0 - 4*it   -> window xs[W-4 .. W+3]  (2 aligned float4)
//   idx2 = V + k + (d>>1) + 1,  V = w0 + 4*it   -> window xs[V   .. V+7]  (2 aligned float4)
// => 4 aligned float4 loads + 8 float4 stores per 128 B of output (1.5 VMEM/store vs 9).
// Nontemporal stores keep the 1.07 GB write stream from thrashing x (2 MiB) out of L2.
// Whole-chunk boundary masking: W,V = 0 (mod 4) so each float4 chunk is entirely
// in-range or entirely out-of-range at the 0 / 512 boundaries.
// Fix vs round 3: __builtin_nontemporal_store needs a real vector type, not
// HIP_vector_type float4 -> use ext_vector_type(4) float.

typedef float f32x4 __attribute__((ext_vector_type(4)));

__global__ __launch_bounds__(256) void StereoConv_kernel(
    const float* __restrict__ x,     // (2, 512, 512) == x[:,0]
    const float* __restrict__ w1p,   // scalar
    const float* __restrict__ w2p,   // scalar
    f32x4* __restrict__ out4)        // (2, 512, 512, 512) as f32x4[.., 128]
{
    const int tid  = blockIdx.x * 256 + threadIdx.x;  // 0 .. 2^19-1
    const int w4   = tid & 127;
    const int h    = (tid >> 7) & 511;
    const int b    = (tid >> 16) & 1;
    const int half = tid >> 17;                       // 0..3 -> it range split

    const float w1 = w1p[0];
    const float w2 = w2p[0];
    const int w0 = w4 << 2;

    const float* __restrict__ row = x + (((b << 9) + h) << 9);  // x[b,h,:]

    for (int t = 0; t < 16; ++t) {
        const int it = (half << 4) | t;    // 0..63
        const int i0 = it << 3;            // 0,8,...,504
        const int W  = w0 - (it << 2);     // left window base (mod 4 == 0)
        const int V  = w0 + (it << 2);     // right window base (mod 4 == 0)

        f32x4 l0 = *(const f32x4*)(row + max(W - 4, 0));   // xs[W-4..W-1], valid iff W >= 4
        f32x4 l1 = *(const f32x4*)(row + max(W, 0));       // xs[W  ..W+3], valid iff W >= 0
        f32x4 r0 = *(const f32x4*)(row + min(V, 508));     // xs[V  ..V+3], valid iff V < 512
        f32x4 r1 = *(const f32x4*)(row + min(V + 4, 508)); // xs[V+4..V+7], valid iff V+4 < 512
        const f32x4 z = {0.f, 0.f, 0.f, 0.f};
        if (W < 4)    l0 = z;
        if (W < 0)    l1 = z;
        if (V >= 512) r0 = z;
        if (V >= 508) r1 = z;

        const float L[8] = {l0.x, l0.y, l0.z, l0.w, l1.x, l1.y, l1.z, l1.w};
        const float R[8] = {r0.x, r0.y, r0.z, r0.w, r1.x, r1.y, r1.z, r1.w};

        // out4 flat index: ((b*512 + i)*512 + h)*128 + w4, i = i0 + d
        const size_t obase = ((((size_t)(b << 9) + i0) << 9 | h) << 7) | w4;

#pragma unroll
        for (int d = 0; d < 8; ++d) {
            const int la = 4 - ((d + 1) >> 1);   // 4,3,3,2,2,1,1,0
            const int ra = (d >> 1) + 1;         // 1,1,2,2,3,3,4,4
            f32x4 v;
            v.x = w1 * L[la + 0] + w2 * R[ra + 0];
            v.y = w1 * L[la + 1] + w2 * R[ra + 1];
            v.z = w1 * L[la + 2] + w2 * R[ra + 2];
            v.w = w1 * L[la + 3] + w2 * R[ra + 3];
            __builtin_nontemporal_store(v, &out4[obase + (size_t)d * (512 * 128)]);
        }
    }
}

extern "C" void kernel_launch(void* const* d_in, const int* in_sizes, int n_in,
                              void* d_out, int out_size, void* d_ws, size_t ws_size,
                              hipStream_t stream) {
    const float* x  = (const float*)d_in[0];
    const float* w1 = (const float*)d_in[1];
    const float* w2 = (const float*)d_in[2];
    f32x4* out4 = (f32x4*)d_out;

    // 2048 blocks * 256 threads * 16 iters * 8 f32x4-stores = 2^30 B = full output
    StereoConv_kernel<<<2048, 256, 0, stream>>>(x, w1, w2, out4);
}

// Round 5
// 198.352 us; speedup vs baseline: 2.0048x; 1.0083x over previous
//
#include <hip/hip_runtime.h>

// out[b,i,h,w] = w1 * (w-s1 >= 0 ? x[b,h,w-s1] : 0) + w2 * (w+s2 < 512 ? x[b,h,w+s2] : 0)
// s1 = (i+1)>>1, s2 = (i>>1)+1.  B=2, I=H=W=512.
//
// Round 5: identical to round 4 EXCEPT plain stores instead of nontemporal —
// A/B on the `nt` flag. fillBufferAligned hits 6.6 TB/s on this buffer with
// plain stores; round 4 (NT) sustained 5.37 TB/s. Single-lever test.
//
// Structure: i-blocked by 8 (i0 = 8*it), per thread per iter:
//   4 aligned f32x4 loads (windows xs[W-4..W+3], xs[V..V+7]) -> 8 f32x4 stores.
// Whole-chunk boundary masking (W,V = 0 mod 4).

typedef float f32x4 __attribute__((ext_vector_type(4)));

__global__ __launch_bounds__(256) void StereoConv_kernel(
    const float* __restrict__ x,     // (2, 512, 512) == x[:,0]
    const float* __restrict__ w1p,   // scalar
    const float* __restrict__ w2p,   // scalar
    f32x4* __restrict__ out4)        // (2, 512, 512, 512) as f32x4[.., 128]
{
    const int tid  = blockIdx.x * 256 + threadIdx.x;  // 0 .. 2^19-1
    const int w4   = tid & 127;
    const int h    = (tid >> 7) & 511;
    const int b    = (tid >> 16) & 1;
    const int half = tid >> 17;                       // 0..3 -> it range split

    const float w1 = w1p[0];
    const float w2 = w2p[0];
    const int w0 = w4 << 2;

    const float* __restrict__ row = x + (((b << 9) + h) << 9);  // x[b,h,:]

    for (int t = 0; t < 16; ++t) {
        const int it = (half << 4) | t;    // 0..63
        const int i0 = it << 3;            // 0,8,...,504
        const int W  = w0 - (it << 2);     // left window base (mod 4 == 0)
        const int V  = w0 + (it << 2);     // right window base (mod 4 == 0)

        f32x4 l0 = *(const f32x4*)(row + max(W - 4, 0));   // xs[W-4..W-1], valid iff W >= 4
        f32x4 l1 = *(const f32x4*)(row + max(W, 0));       // xs[W  ..W+3], valid iff W >= 0
        f32x4 r0 = *(const f32x4*)(row + min(V, 508));     // xs[V  ..V+3], valid iff V < 512
        f32x4 r1 = *(const f32x4*)(row + min(V + 4, 508)); // xs[V+4..V+7], valid iff V+4 < 512
        const f32x4 z = {0.f, 0.f, 0.f, 0.f};
        if (W < 4)    l0 = z;
        if (W < 0)    l1 = z;
        if (V >= 512) r0 = z;
        if (V >= 508) r1 = z;

        const float L[8] = {l0.x, l0.y, l0.z, l0.w, l1.x, l1.y, l1.z, l1.w};
        const float R[8] = {r0.x, r0.y, r0.z, r0.w, r1.x, r1.y, r1.z, r1.w};

        // out4 flat index: ((b*512 + i)*512 + h)*128 + w4, i = i0 + d
        const size_t obase = ((((size_t)(b << 9) + i0) << 9 | h) << 7) | w4;

#pragma unroll
        for (int d = 0; d < 8; ++d) {
            const int la = 4 - ((d + 1) >> 1);   // 4,3,3,2,2,1,1,0
            const int ra = (d >> 1) + 1;         // 1,1,2,2,3,3,4,4
            f32x4 v;
            v.x = w1 * L[la + 0] + w2 * R[ra + 0];
            v.y = w1 * L[la + 1] + w2 * R[ra + 1];
            v.z = w1 * L[la + 2] + w2 * R[ra + 2];
            v.w = w1 * L[la + 3] + w2 * R[ra + 3];
            out4[obase + (size_t)d * (512 * 128)] = v;   // plain store (A/B vs NT)
        }
    }
}

extern "C" void kernel_launch(void* const* d_in, const int* in_sizes, int n_in,
                              void* d_out, int out_size, void* d_ws, size_t ws_size,
                              hipStream_t stream) {
    const float* x  = (const float*)d_in[0];
    const float* w1 = (const float*)d_in[1];
    const float* w2 = (const float*)d_in[2];
    f32x4* out4 = (f32x4*)d_out;

    // 2048 blocks * 256 threads * 16 iters * 8 f32x4-stores = 2^30 B = full output
    StereoConv_kernel<<<2048, 256, 0, stream>>>(x, w1, w2, out4);
}

// Round 6
// 189.222 us; speedup vs baseline: 2.1016x; 1.0482x over previous
//
#include <hip/hip_runtime.h>

// out[b,i,h,w] = w1 * (w-s1 >= 0 ? x[b,h,w-s1] : 0) + w2 * (w+s2 < 512 ? x[b,h,w+s2] : 0)
// s1 = (i+1)>>1, s2 = (i>>1)+1.  B=2, I=H=W=512.
//
// Round 6: LDS-stage the block's 2 x-rows (4 KB) once, serve all window reads
// from LDS. Kills the ~0.5 GB global read stream that was sharing the
// XCD<->IC/HBM fabric with the 1.07 GB write stream (round-5 theory: reads
// miss write-thrashed L2, fall to Infinity Cache, contend with stores).
// Global reads: 512 MiB -> 8 MiB. Store structure identical to round 5
// (i-blocked by 8, whole-chunk boundary masking, plain f32x4 stores).

typedef float f32x4 __attribute__((ext_vector_type(4)));

__global__ __launch_bounds__(256) void StereoConv_kernel(
    const float* __restrict__ x,     // (2, 512, 512) == x[:,0]
    const float* __restrict__ w1p,   // scalar
    const float* __restrict__ w2p,   // scalar
    f32x4* __restrict__ out4)        // (2, 512, 512, 512) as f32x4[.., 128]
{
    __shared__ __align__(16) float lds[2][512];   // this block's 2 x-rows

    const int tid  = blockIdx.x * 256 + threadIdx.x;  // 0 .. 2^19-1
    const int w4   = tid & 127;
    const int h    = (tid >> 7) & 511;                // = 2*blockIdx + (threadIdx>>7), mod 512
    const int b    = (tid >> 16) & 1;                 // block-uniform
    const int half = tid >> 17;                       // 0..3, block-uniform

    // ---- stage: 2 rows x 512 floats = 256 f32x4, one per thread ----
    {
        const int r = threadIdx.x >> 7;               // 0..1
        const int c = threadIdx.x & 127;              // f32x4 column
        const int hbase = (blockIdx.x * 2) & 511;     // block's first h (even)
        const float* srcrow = x + (((b << 9) + hbase + r) << 9);
        *(f32x4*)&lds[r][c << 2] = *(const f32x4*)(srcrow + (c << 2));
    }
    __syncthreads();

    const float w1 = w1p[0];
    const float w2 = w2p[0];
    const int w0 = w4 << 2;
    const float* __restrict__ row = &lds[threadIdx.x >> 7][0];   // this thread's x-row

    for (int t = 0; t < 16; ++t) {
        const int it = (half << 4) | t;    // 0..63
        const int i0 = it << 3;            // 0,8,...,504
        const int W  = w0 - (it << 2);     // left window base (mod 4 == 0)
        const int V  = w0 + (it << 2);     // right window base (mod 4 == 0)

        f32x4 l0 = *(const f32x4*)(row + max(W - 4, 0));   // xs[W-4..W-1], valid iff W >= 4
        f32x4 l1 = *(const f32x4*)(row + max(W, 0));       // xs[W  ..W+3], valid iff W >= 0
        f32x4 r0 = *(const f32x4*)(row + min(V, 508));     // xs[V  ..V+3], valid iff V < 512
        f32x4 r1 = *(const f32x4*)(row + min(V + 4, 508)); // xs[V+4..V+7], valid iff V+4 < 512
        const f32x4 z = {0.f, 0.f, 0.f, 0.f};
        if (W < 4)    l0 = z;
        if (W < 0)    l1 = z;
        if (V >= 512) r0 = z;
        if (V >= 508) r1 = z;

        const float L[8] = {l0.x, l0.y, l0.z, l0.w, l1.x, l1.y, l1.z, l1.w};
        const float R[8] = {r0.x, r0.y, r0.z, r0.w, r1.x, r1.y, r1.z, r1.w};

        // out4 flat index: ((b*512 + i)*512 + h)*128 + w4, i = i0 + d
        const size_t obase = ((((size_t)(b << 9) + i0) << 9 | h) << 7) | w4;

#pragma unroll
        for (int d = 0; d < 8; ++d) {
            const int la = 4 - ((d + 1) >> 1);   // 4,3,3,2,2,1,1,0
            const int ra = (d >> 1) + 1;         // 1,1,2,2,3,3,4,4
            f32x4 v;
            v.x = w1 * L[la + 0] + w2 * R[ra + 0];
            v.y = w1 * L[la + 1] + w2 * R[ra + 1];
            v.z = w1 * L[la + 2] + w2 * R[ra + 2];
            v.w = w1 * L[la + 3] + w2 * R[ra + 3];
            out4[obase + (size_t)d * (512 * 128)] = v;
        }
    }
}

extern "C" void kernel_launch(void* const* d_in, const int* in_sizes, int n_in,
                              void* d_out, int out_size, void* d_ws, size_t ws_size,
                              hipStream_t stream) {
    const float* x  = (const float*)d_in[0];
    const float* w1 = (const float*)d_in[1];
    const float* w2 = (const float*)d_in[2];
    f32x4* out4 = (f32x4*)d_out;

    // 2048 blocks * 256 threads * 16 iters * 8 f32x4-stores = 2^30 B = full output
    StereoConv_kernel<<<2048, 256, 0, stream>>>(x, w1, w2, out4);
}